// Round 4
// baseline (120.989 us; speedup 1.0000x reference)
//
#include <hip/hip_runtime.h>

// ---------------------------------------------------------------------------
// SgpiSTFT: Hermitian iFFT (as GEMM vs fixed cos/sin matrix) + window + 4-tap
// overlap-add + flip/transpose, fused.
//
//   y[n,t] = Re(c0) + 2*sum_{k=1..255}( Re_k cos(2pi n k/512) + Im_k sin(...) )
//   out[b, t*256 + (255-j)] = 256*( y[256+j,t]  *win[768+j]
//                                  + y[j,  t-1] *win[512+j]
//                                  + y[256+j,t-2]*win[256+j]
//                                  + y[j,  t-3] *win[j] )
// Symmetry: y[256+j] flips sign of odd-k terms -> accumulate even-k (E) and
// odd-k (O) halves; Y=E+O, Yh=E-O.
//
// Round-4 = round-3 with the compile fix (manual bf16 pair pack instead of
// bit_cast of __hip_bfloat162): XCD-batch grid mapping (b=bid&7),
// launch_bounds(512,4), depth-2 M prefetch, depth-1 LDS a-frag prefetch,
// send-side-select epilogue (half the bpermutes), additive LDS swizzle,
// packed f32->bf16 conversion.
// ---------------------------------------------------------------------------

typedef __attribute__((ext_vector_type(8))) short short8;
typedef __attribute__((ext_vector_type(8))) __bf16 bf16x8;
typedef __attribute__((ext_vector_type(4))) float floatx4;
typedef __attribute__((ext_vector_type(4))) unsigned uintx4;

__device__ inline unsigned bfbits(float f) {
  unsigned u = __builtin_bit_cast(unsigned, f);
  return (u + 0x7fffu + ((u >> 16) & 1u)) >> 16;  // RNE, low 16 bits valid
}

__device__ inline short f2bf(float f) { return (short)(unsigned short)bfbits(f); }

__device__ inline unsigned pk2bf(float a, float b) {
  return (bfbits(a) & 0xffffu) | (bfbits(b) << 16);
}

#define PI_OVER_256 0.01227184630308513f

// M matrix in MFMA B-fragment order (validated rounds 1-2):
//   frag idx = (Jtile*16 + s)*64 + lane ; lane holds row j = Jtile*16+(lane&15),
//   kappa = s*32 + (lane>>4)*8 + e, e=0..7 (one short8 per lane).
//   kappa < 256: gk = 2*kappa (even);  kappa >= 256: gk = 2*(kappa-256)+1 (odd)
//   M[j][gk] = (gk==0) ? 1 : (gk<256 ? 2cos(2pi j gk/512) : 2sin(2pi j (gk-256)/512))
__global__ void build_m(short* __restrict__ M) {
  int idx = blockIdx.x * blockDim.x + threadIdx.x;  // [0, 16*16*64)
  int ntile = idx >> 10;
  int s = (idx >> 6) & 15;
  int lane = idx & 63;
  int n = ntile * 16 + (lane & 15);
  int kb = lane >> 4;
  short8 v;
#pragma unroll
  for (int e = 0; e < 8; e++) {
    int kap = s * 32 + kb * 8 + e;
    int gk = 2 * (kap & 255) + (kap >> 8);
    float val;
    if (gk == 0) {
      val = 1.0f;
    } else if (gk < 256) {
      int m = (n * gk) & 511;
      val = 2.0f * __cosf((float)m * PI_OVER_256);
    } else {
      int m = (n * (gk - 256)) & 511;
      val = 2.0f * __sinf((float)m * PI_OVER_256);
    }
    v[e] = f2bf(val);
  }
  ((short8*)M)[idx] = v;
}

// LDS swizzle: element offset (shorts) = col*512 + slot(g,col)*8, where g =
// kappa/8 and slot = (g&56) | ((g+col)&7). Additive low bits are dense (8
// distinct bank groups) for BOTH the staging write lane-pattern (col=4*(l&7)+cc,
// g=l>>3) and the fragment read pattern (col=l&15, g=4s+(l>>4)).
__device__ inline int lds_off(int col, int g) {
  return col * 512 + (((g & 56) | ((g + col) & 7)) << 3);
}

// Block: batch b = bid&7 (one batch per XCD), tile = bid>>3. X columns
// [c0, c0+32), c0 = 28*tile - 4 (halo 4). Outputs L in [4,32) -> t = c0+L,
// masked to t <= 3998. 512 threads = 8 waves; wave w owns j-tiles {2w, 2w+1}.
__global__ __launch_bounds__(512, 4) void gemm_ola(
    const float* __restrict__ in, const float* __restrict__ win,
    const short* __restrict__ M, float* __restrict__ out) {
  __shared__ short ldsX[32 * 512];  // 32 KiB

  const int tid = threadIdx.x;
  const int bid = blockIdx.x;
  const int b = bid & 7;
  const int tile = bid >> 3;
  const int c0 = 28 * tile - 4;

  // ---- stage X: dwordx4 global loads + register transpose -> bf16 LDS ----
  {
    const int cbase = 4 * (tid & 7);  // 4 consecutive cols
    const int gg = tid >> 3;          // kappa-group (8 kappa)
    const int kap0 = gg * 8;
    const int gc = c0 + cbase;
    floatx4 f[8];
    if (gc >= 0 && gc <= 3996) {
      const float* src = in + (size_t)b * 2056000 + gc;
#pragma unroll
      for (int j = 0; j < 8; j++) {
        int kap = kap0 + j;
        int gk = 2 * (kap & 255) + (kap >> 8);
        int row = (gk < 256) ? gk : gk + 1;  // imag rows start at 257
        f[j] = *(const floatx4*)(src + (size_t)row * 4000);
      }
    } else {
#pragma unroll
      for (int j = 0; j < 8; j++) f[j] = floatx4{0.f, 0.f, 0.f, 0.f};
    }
#pragma unroll
    for (int cc = 0; cc < 4; cc++) {
      const int col = cbase + cc;
      uintx4 u;
#pragma unroll
      for (int i = 0; i < 4; i++) u[i] = pk2bf(f[2 * i][cc], f[2 * i + 1][cc]);
      *(uintx4*)&ldsX[lds_off(col, gg)] = u;
    }
  }
  __syncthreads();

  const int w = tid >> 6;
  const int lane = tid & 63;
  const int c = lane & 15;   // MFMA spatial index within 16-tile
  const int kb = lane >> 4;  // k-block; also C row-group rg
  const int rg = kb;

  // acc[q][jt]: q = t-tile (C rows = t), jt = j-tile (C cols = j)
  floatx4 accE[2][2] = {};
  floatx4 accO[2][2] = {};

  const short8* Mf = (const short8*)M;
  const int J0 = 2 * w, J1 = 2 * w + 1;

  // depth-2 pipeline on M (L2-resident) fragments
  bf16x8 c00 = __builtin_bit_cast(bf16x8, Mf[(J0 * 16 + 0) * 64 + lane]);
  bf16x8 c01 = __builtin_bit_cast(bf16x8, Mf[(J1 * 16 + 0) * 64 + lane]);
  bf16x8 n00 = __builtin_bit_cast(bf16x8, Mf[(J0 * 16 + 1) * 64 + lane]);
  bf16x8 n01 = __builtin_bit_cast(bf16x8, Mf[(J1 * 16 + 1) * 64 + lane]);
  // depth-1 pipeline on LDS a-frags
  bf16x8 a0 = __builtin_bit_cast(bf16x8, *(const short8*)&ldsX[lds_off(c, kb)]);
  bf16x8 a1 = __builtin_bit_cast(bf16x8, *(const short8*)&ldsX[lds_off(16 + c, kb)]);

#pragma unroll
  for (int s = 0; s < 16; s++) {
    bf16x8 f00, f01, na0, na1;
    if (s < 14) {
      f00 = __builtin_bit_cast(bf16x8, Mf[(J0 * 16 + s + 2) * 64 + lane]);
      f01 = __builtin_bit_cast(bf16x8, Mf[(J1 * 16 + s + 2) * 64 + lane]);
    }
    if (s < 15) {
      const int g = 4 * (s + 1) + kb;
      na0 = __builtin_bit_cast(bf16x8, *(const short8*)&ldsX[lds_off(c, g)]);
      na1 = __builtin_bit_cast(bf16x8, *(const short8*)&ldsX[lds_off(16 + c, g)]);
    }
    if (s < 8) {
      accE[0][0] = __builtin_amdgcn_mfma_f32_16x16x32_bf16(a0, c00, accE[0][0], 0, 0, 0);
      accE[0][1] = __builtin_amdgcn_mfma_f32_16x16x32_bf16(a0, c01, accE[0][1], 0, 0, 0);
      accE[1][0] = __builtin_amdgcn_mfma_f32_16x16x32_bf16(a1, c00, accE[1][0], 0, 0, 0);
      accE[1][1] = __builtin_amdgcn_mfma_f32_16x16x32_bf16(a1, c01, accE[1][1], 0, 0, 0);
    } else {
      accO[0][0] = __builtin_amdgcn_mfma_f32_16x16x32_bf16(a0, c00, accO[0][0], 0, 0, 0);
      accO[0][1] = __builtin_amdgcn_mfma_f32_16x16x32_bf16(a0, c01, accO[0][1], 0, 0, 0);
      accO[1][0] = __builtin_amdgcn_mfma_f32_16x16x32_bf16(a1, c00, accO[1][0], 0, 0, 0);
      accO[1][1] = __builtin_amdgcn_mfma_f32_16x16x32_bf16(a1, c01, accO[1][1], 0, 0, 0);
    }
    c00 = n00; c01 = n01; n00 = f00; n01 = f01;
    a0 = na0; a1 = na1;
  }

  // ---- OLA epilogue ----
  // C layout: col (lane&15) = j within j-tile; row (rg*4+p) = local t offset.
  // Tap t-d = reg p-d; p-d<0 borrows reg p-d+4 from source lane
  // sl = (lane+48)&63 (row-group rg-1, or rg=3 of tile q-1 when rg==0).
  // Send-side select: source lane with rg==3 sends tile q-1's value.
#pragma unroll
  for (int jt = 0; jt < 2; jt++) {
    const int J = 2 * w + jt;
    const int j = 16 * J + c;
    const float wv0 = 256.0f * win[768 + j];
    const float wv1 = 256.0f * win[512 + j];
    const float wv2 = 256.0f * win[256 + j];
    const float wv3 = 256.0f * win[j];

    floatx4 Y[2], Yh[2];
#pragma unroll
    for (int q = 0; q < 2; q++) {
      Y[q] = accE[q][jt] + accO[q][jt];
      Yh[q] = accE[q][jt] - accO[q][jt];
    }

#pragma unroll
    for (int q = 0; q < 2; q++) {
      const int qm = (q > 0) ? q - 1 : 0;  // q==0 borrow lanes are masked out
      float yb[4], yhb[4];
#pragma unroll
      for (int p = 1; p < 4; p++) {
        float z = (rg == 3) ? Y[qm][p] : Y[q][p];
        yb[p] = __shfl(z, lane + 48, 64);
      }
#pragma unroll
      for (int p = 2; p < 4; p++) {
        float z = (rg == 3) ? Yh[qm][p] : Yh[q][p];
        yhb[p] = __shfl(z, lane + 48, 64);
      }
      floatx4 v;
#pragma unroll
      for (int p = 0; p < 4; p++) {
        float t1 = (p >= 1) ? Y[q][p - 1] : yb[3];
        float t2 = (p >= 2) ? Yh[q][p - 2] : yhb[p + 2];
        float t3 = (p >= 3) ? Y[q][p - 3] : yb[p + 1];
        v[p] = wv0 * Yh[q][p] + wv1 * t1 + wv2 * t2 + wv3 * t3;
      }
#pragma unroll
      for (int p = 0; p < 4; p++) {
        const int L = 16 * q + 4 * rg + p;
        const int t = c0 + L;
        if (L >= 4 && t <= 3998) {
          out[((size_t)b * 3999 + t) * 256 + (255 - j)] = v[p];
        }
      }
    }
  }
}

extern "C" void kernel_launch(void* const* d_in, const int* in_sizes, int n_in,
                              void* d_out, int out_size, void* d_ws, size_t ws_size,
                              hipStream_t stream) {
  const float* in = (const float*)d_in[0];   // (8, 514, 4000) fp32
  const float* win = (const float*)d_in[1];  // (1024,) fp32
  float* out = (float*)d_out;                // (8, 3999*256) fp32
  short* M = (short*)d_ws;                   // 256 KiB bf16 coefficient matrix

  hipLaunchKernelGGL(build_m, dim3(64), dim3(256), 0, stream, M);
  // 143 tiles/batch * 8 batches; b = bid&7 -> one batch per XCD (bid%8 maps
  // round-robin to XCDs), tile = bid>>3 -> contiguous tiles share L2 lines.
  hipLaunchKernelGGL(gemm_ola, dim3(1144), dim3(512), 0, stream, in, win, M, out);
}